// Round 1
// baseline (614.690 us; speedup 1.0000x reference)
//
#include <hip/hip_runtime.h>
#include <math.h>

#define NN 50000
#define NE 800000
#define TW 10

static __device__ __forceinline__ float sigf(float x){ return 1.0f/(1.0f+__expf(-x)); }
static __device__ __forceinline__ float tanhfast(float x){
  float e2 = __expf(2.0f*x);
  return 1.0f - 2.0f/(e2 + 1.0f);
}

// ---------------- degree / norms ----------------
__global__ void k_degree(const int* __restrict__ src, const int* __restrict__ dst,
                         int* __restrict__ dego, int* __restrict__ degi){
  int e = blockIdx.x*256 + threadIdx.x;
  if (e < NE){
    atomicAdd(&dego[src[e]], 1);
    atomicAdd(&degi[dst[e]], 1);
  }
}

__global__ void k_norm(const int* __restrict__ dego, const int* __restrict__ degi,
                       float* __restrict__ ns, float* __restrict__ nd,
                       unsigned* __restrict__ maxbuf){
  int i = blockIdx.x*256 + threadIdx.x;
  if (i < NN){
    int a = dego[i]; if (a < 1) a = 1;
    int b = degi[i]; if (b < 1) b = 1;
    ns[i] = rsqrtf((float)a);
    nd[i] = rsqrtf((float)b);
  }
  if (blockIdx.x == 0 && threadIdx.x < 8) maxbuf[threadIdx.x] = 0x3FFFFFFFu; // map(-2.0f)
}

// ---------------- prefix scan for CSR row_start ----------------
__global__ void k_scan1(const int* __restrict__ degi, int* __restrict__ bsum){
  __shared__ int s[512];
  int i = blockIdx.x*512 + threadIdx.x;
  s[threadIdx.x] = (i < NN) ? degi[i] : 0;
  __syncthreads();
  for (int st = 256; st > 0; st >>= 1){
    if (threadIdx.x < st) s[threadIdx.x] += s[threadIdx.x + st];
    __syncthreads();
  }
  if (threadIdx.x == 0) bsum[blockIdx.x] = s[0];
}

__global__ void k_scan2(int* __restrict__ bsum, int nb, int* __restrict__ row_start){
  if (blockIdx.x == 0 && threadIdx.x == 0){
    int run = 0;
    for (int b = 0; b < nb; ++b){ int v = bsum[b]; bsum[b] = run; run += v; }
    row_start[NN] = run;
  }
}

__global__ void k_scan3(const int* __restrict__ degi, const int* __restrict__ boff,
                        int* __restrict__ row_start){
  __shared__ int s[512];
  int i = blockIdx.x*512 + threadIdx.x;
  int v = (i < NN) ? degi[i] : 0;
  s[threadIdx.x] = v;
  __syncthreads();
  for (int st = 1; st < 512; st <<= 1){
    int add = (threadIdx.x >= st) ? s[threadIdx.x - st] : 0;
    __syncthreads();
    s[threadIdx.x] += add;
    __syncthreads();
  }
  if (i < NN) row_start[i] = boff[blockIdx.x] + s[threadIdx.x] - v; // exclusive
}

__global__ void k_fill(const int* __restrict__ src, const int* __restrict__ dst,
                       const int* __restrict__ row_start, int* __restrict__ cursor,
                       int* __restrict__ csr){
  int e = blockIdx.x*256 + threadIdx.x;
  if (e < NE){
    int d = dst[e];
    int p = atomicAdd(&cursor[d], 1);
    csr[row_start[d] + p] = src[e];
  }
}

// ---------------- conv1 matmul: h1 = (feat * ns) @ W1  (500k rows, K=128 -> 8) ----------------
__global__ __launch_bounds__(256) void k_conv1(const float* __restrict__ feat,
                                               const float* __restrict__ W1,
                                               const float* __restrict__ ns,
                                               float* __restrict__ h1){
  __shared__ float4 w[256];            // W1[d][0..3], W1[d][4..7] -> w[d*2+q]
  int tid = threadIdx.x;
  w[tid] = ((const float4*)W1)[tid];   // 256 float4 = 1024 floats
  __syncthreads();
  long long r = (long long)blockIdx.x*256 + tid;
  if (r >= (long long)TW*NN) return;
  const float4* frow = (const float4*)feat + r*32;
  float a0x=0,a0y=0,a0z=0,a0w=0, a1x=0,a1y=0,a1z=0,a1w=0;
  #pragma unroll
  for (int d4 = 0; d4 < 32; ++d4){
    float4 f = frow[d4];
    #pragma unroll
    for (int c = 0; c < 4; ++c){
      float fv = (c==0)?f.x:((c==1)?f.y:((c==2)?f.z:f.w));
      float4 wa = w[(d4*4+c)*2 + 0];
      float4 wb = w[(d4*4+c)*2 + 1];
      a0x += fv*wa.x; a0y += fv*wa.y; a0z += fv*wa.z; a0w += fv*wa.w;
      a1x += fv*wb.x; a1y += fv*wb.y; a1z += fv*wb.z; a1w += fv*wb.w;
    }
  }
  int node = (int)(r % NN);
  float sc = ns[node];
  float4 o0 = { a0x*sc, a0y*sc, a0z*sc, a0w*sc };
  float4 o1 = { a1x*sc, a1y*sc, a1z*sc, a1w*sc };
  float4* out = (float4*)h1 + r*2;
  out[0] = o0; out[1] = o1;
}

// ---------------- aggregate1 + conv1 epilogue (+pre-scale for layer2) ----------------
__global__ __launch_bounds__(256) void k_agg1(const float* __restrict__ h1,
                                              const int* __restrict__ row_start,
                                              const int* __restrict__ csr,
                                              const float* __restrict__ ns,
                                              const float* __restrict__ nd,
                                              const float* __restrict__ b1,
                                              float* __restrict__ x2p){
  int gid = blockIdx.x*256 + threadIdx.x;
  if (gid >= TW*NN) return;
  int t = gid / NN, n = gid - t*NN;
  const float4* base = (const float4*)h1 + (long long)t*NN*2;
  float a0x=0,a0y=0,a0z=0,a0w=0, a1x=0,a1y=0,a1z=0,a1w=0;
  int e0 = row_start[n], e1 = row_start[n+1];
  for (int e = e0; e < e1; ++e){
    int s = csr[e];
    float4 v0 = base[(long long)s*2 + 0];
    float4 v1 = base[(long long)s*2 + 1];
    a0x += v0.x; a0y += v0.y; a0z += v0.z; a0w += v0.w;
    a1x += v1.x; a1y += v1.y; a1z += v1.z; a1w += v1.w;
  }
  float sc = nd[n];
  float osc = ns[n];  // layer-2 source-norm pre-scale folded in
  float4 o0, o1;
  o0.x = fmaxf(a0x*sc + b1[0], 0.f)*osc;
  o0.y = fmaxf(a0y*sc + b1[1], 0.f)*osc;
  o0.z = fmaxf(a0z*sc + b1[2], 0.f)*osc;
  o0.w = fmaxf(a0w*sc + b1[3], 0.f)*osc;
  o1.x = fmaxf(a1x*sc + b1[4], 0.f)*osc;
  o1.y = fmaxf(a1y*sc + b1[5], 0.f)*osc;
  o1.z = fmaxf(a1z*sc + b1[6], 0.f)*osc;
  o1.w = fmaxf(a1w*sc + b1[7], 0.f)*osc;
  float4* out = (float4*)x2p + (long long)gid*2;
  out[0] = o0; out[1] = o1;
}

// ---------------- aggregate2 + W2 epilogue + LSTM input projection ----------------
__global__ __launch_bounds__(256) void k_agg2(const float* __restrict__ x2p,
                                              const int* __restrict__ row_start,
                                              const int* __restrict__ csr,
                                              const float* __restrict__ nd,
                                              const float* __restrict__ W2,
                                              const float* __restrict__ b2,
                                              const float* __restrict__ Wih,
                                              const float* __restrict__ bih,
                                              const float* __restrict__ bhh,
                                              float* __restrict__ xg){
  __shared__ float w2[128];     // (8,16) row-major
  __shared__ float4 wih[128];   // (32,16) row-major as float4
  __shared__ float bsum[32];
  __shared__ float b2s[16];
  int tid = threadIdx.x;
  if (tid < 128){ w2[tid] = W2[tid]; wih[tid] = ((const float4*)Wih)[tid]; }
  if (tid < 32) bsum[tid] = bih[tid] + bhh[tid];
  if (tid < 16) b2s[tid] = b2[tid];
  __syncthreads();
  int gid = blockIdx.x*256 + tid;
  if (gid >= TW*NN) return;
  int t = gid / NN, n = gid - t*NN;
  const float4* base = (const float4*)x2p + (long long)t*NN*2;
  float acc[8] = {0,0,0,0,0,0,0,0};
  int e0 = row_start[n], e1 = row_start[n+1];
  for (int e = e0; e < e1; ++e){
    int s = csr[e];
    float4 v0 = base[(long long)s*2 + 0];
    float4 v1 = base[(long long)s*2 + 1];
    acc[0]+=v0.x; acc[1]+=v0.y; acc[2]+=v0.z; acc[3]+=v0.w;
    acc[4]+=v1.x; acc[5]+=v1.y; acc[6]+=v1.z; acc[7]+=v1.w;
  }
  float sc = nd[n];
  float y[16];
  #pragma unroll
  for (int j = 0; j < 16; ++j){
    float s = 0.f;
    #pragma unroll
    for (int k = 0; k < 8; ++k) s += acc[k]*w2[k*16 + j];
    y[j] = fmaxf(s*sc + b2s[j], 0.f);
  }
  // xg[g] = bsum[g] + y . Wih[g][:]
  float4* out = (float4*)xg + (long long)gid*8;
  #pragma unroll
  for (int g4 = 0; g4 < 8; ++g4){
    float4 o;
    #pragma unroll
    for (int c = 0; c < 4; ++c){
      int g = g4*4 + c;
      float s = bsum[g];
      #pragma unroll
      for (int q = 0; q < 4; ++q){
        float4 wv = wih[g*4 + q];
        s += y[q*4+0]*wv.x + y[q*4+1]*wv.y + y[q*4+2]*wv.z + y[q*4+3]*wv.w;
      }
      if (c==0) o.x = s; else if (c==1) o.y = s; else if (c==2) o.z = s; else o.w = s;
    }
    out[g4] = o;
  }
}

// ---------------- LSTM over T=10 + max-pool reduce ----------------
__global__ __launch_bounds__(256) void k_lstm(const float* __restrict__ xg,
                                              const float* __restrict__ Whh,
                                              unsigned* __restrict__ maxbuf){
  __shared__ float4 whh[64];   // (32,8) row-major as float4: whh[g*2+q]
  __shared__ unsigned smax[8];
  int tid = threadIdx.x;
  if (tid < 64) whh[tid] = ((const float4*)Whh)[tid];
  if (tid < 8) smax[tid] = 0u;
  __syncthreads();
  int n = blockIdx.x*256 + tid;
  if (n < NN){
    float h[8] = {0,0,0,0,0,0,0,0};
    float c[8] = {0,0,0,0,0,0,0,0};
    for (int t = 0; t < TW; ++t){
      const float4* xr = (const float4*)xg + ((long long)t*NN + n)*8;
      float g[32];
      #pragma unroll
      for (int q = 0; q < 8; ++q){
        float4 v = xr[q];
        g[q*4+0]=v.x; g[q*4+1]=v.y; g[q*4+2]=v.z; g[q*4+3]=v.w;
      }
      #pragma unroll
      for (int gi = 0; gi < 32; ++gi){
        float4 wa = whh[gi*2+0], wb = whh[gi*2+1];
        g[gi] += h[0]*wa.x + h[1]*wa.y + h[2]*wa.z + h[3]*wa.w
               + h[4]*wb.x + h[5]*wb.y + h[6]*wb.z + h[7]*wb.w;
      }
      #pragma unroll
      for (int j = 0; j < 8; ++j){
        float ig = sigf(g[j]);
        float fg = sigf(g[8+j]);
        float gg = tanhfast(g[16+j]);
        float og = sigf(g[24+j]);
        c[j] = fg*c[j] + ig*gg;
        h[j] = og*tanhfast(c[j]);
      }
    }
    #pragma unroll
    for (int j = 0; j < 8; ++j){
      unsigned b = __float_as_uint(h[j]);
      unsigned u = (b & 0x80000000u) ? ~b : (b | 0x80000000u); // monotonic map
      atomicMax(&smax[j], u);
    }
  }
  __syncthreads();
  if (tid < 8) atomicMax(&maxbuf[tid], smax[tid]);
}

// ---------------- head ----------------
__global__ void k_final(const unsigned* __restrict__ maxbuf,
                        const float* __restrict__ Wo, const float* __restrict__ bo,
                        float* __restrict__ out){
  if (blockIdx.x == 0 && threadIdx.x == 0){
    float m[8];
    #pragma unroll
    for (int j = 0; j < 8; ++j){
      unsigned u = maxbuf[j];
      unsigned b = (u & 0x80000000u) ? (u ^ 0x80000000u) : ~u;
      m[j] = __uint_as_float(b);
    }
    #pragma unroll
    for (int o = 0; o < 4; ++o){
      float s = bo[o];
      #pragma unroll
      for (int k = 0; k < 8; ++k) s += m[k]*Wo[k*4 + o];
      out[o] = 1.0f/(1.0f + __expf(-s));
    }
  }
}

extern "C" void kernel_launch(void* const* d_in, const int* in_sizes, int n_in,
                              void* d_out, int out_size, void* d_ws, size_t ws_size,
                              hipStream_t stream) {
  const float* feat = (const float*)d_in[0];
  const int*   src  = (const int*)d_in[1];
  const int*   dst  = (const int*)d_in[2];
  const float* W1   = (const float*)d_in[3];
  const float* b1   = (const float*)d_in[4];
  const float* W2   = (const float*)d_in[5];
  const float* b2   = (const float*)d_in[6];
  const float* Wih  = (const float*)d_in[7];
  const float* Whh  = (const float*)d_in[8];
  const float* bih  = (const float*)d_in[9];
  const float* bhh  = (const float*)d_in[10];
  const float* Wo   = (const float*)d_in[11];
  const float* bo   = (const float*)d_in[12];
  float* out = (float*)d_out;

  // workspace layout (all offsets 256B-aligned)
  const size_t SN = 50048; // padded node stride
  int*      dego      = (int*)d_ws;
  int*      degi      = dego + SN;
  int*      cursor    = degi + SN;
  float*    ns        = (float*)(cursor + SN);
  float*    nd        = ns + SN;
  int*      row_start = (int*)(nd + SN);       // 50001 used, 50304 reserved
  int*      bsum      = row_start + 50304;     // 128
  unsigned* maxbuf    = (unsigned*)(bsum + 128); // 8 used, 64 reserved
  int*      csr       = (int*)(maxbuf + 64);   // 800000
  float*    h1        = (float*)(csr + 800000);   // 4,000,000
  float*    x2p       = h1 + 4000000;             // 4,000,000
  float*    xg        = x2p + 4000000;            // 16,000,000

  hipMemsetAsync(dego, 0, 3*SN*sizeof(int), stream);

  const int B = 256;
  k_degree<<<(NE + B - 1)/B, B, 0, stream>>>(src, dst, dego, degi);
  k_norm  <<<(NN + B - 1)/B, B, 0, stream>>>(dego, degi, ns, nd, maxbuf);

  const int NB = (NN + 511)/512; // 98
  k_scan1<<<NB, 512, 0, stream>>>(degi, bsum);
  k_scan2<<<1, 64, 0, stream>>>(bsum, NB, row_start);
  k_scan3<<<NB, 512, 0, stream>>>(degi, bsum, row_start);
  k_fill <<<(NE + B - 1)/B, B, 0, stream>>>(src, dst, row_start, cursor, csr);

  const int RTOT = TW*NN; // 500000 rows
  k_conv1<<<(RTOT + B - 1)/B, B, 0, stream>>>(feat, W1, ns, h1);
  k_agg1 <<<(RTOT + B - 1)/B, B, 0, stream>>>(h1, row_start, csr, ns, nd, b1, x2p);
  k_agg2 <<<(RTOT + B - 1)/B, B, 0, stream>>>(x2p, row_start, csr, nd, W2, b2, Wih, bih, bhh, xg);
  k_lstm <<<(NN + B - 1)/B, B, 0, stream>>>(xg, Whh, maxbuf);
  k_final<<<1, 64, 0, stream>>>(maxbuf, Wo, bo, out);
}

// Round 2
// 387.399 us; speedup vs baseline: 1.5867x; 1.5867x over previous
//
#include <hip/hip_runtime.h>
#include <math.h>

#define NN 50000
#define NE 800000
#define TW 10

static __device__ __forceinline__ float sigf(float x){ return 1.0f/(1.0f+__expf(-x)); }
static __device__ __forceinline__ float tanhfast(float x){
  float e2 = __expf(2.0f*x);
  return 1.0f - 2.0f/(e2 + 1.0f);
}

// ---------------- degree / norms ----------------
__global__ void k_degree(const int* __restrict__ src, const int* __restrict__ dst,
                         int* __restrict__ dego, int* __restrict__ degi){
  int e = blockIdx.x*256 + threadIdx.x;
  if (e < NE){
    atomicAdd(&dego[src[e]], 1);
    atomicAdd(&degi[dst[e]], 1);
  }
}

__global__ void k_norm(const int* __restrict__ dego, const int* __restrict__ degi,
                       float* __restrict__ ns, float* __restrict__ nd,
                       unsigned* __restrict__ maxbuf){
  int i = blockIdx.x*256 + threadIdx.x;
  if (i < NN){
    int a = dego[i]; if (a < 1) a = 1;
    int b = degi[i]; if (b < 1) b = 1;
    ns[i] = rsqrtf((float)a);
    nd[i] = rsqrtf((float)b);
  }
  if (blockIdx.x == 0 && threadIdx.x < 8) maxbuf[threadIdx.x] = 0x3FFFFFFFu; // map(-2.0f)
}

// ---------------- prefix scan for CSR row_start ----------------
__global__ void k_scan1(const int* __restrict__ degi, int* __restrict__ bsum){
  __shared__ int s[512];
  int i = blockIdx.x*512 + threadIdx.x;
  s[threadIdx.x] = (i < NN) ? degi[i] : 0;
  __syncthreads();
  for (int st = 256; st > 0; st >>= 1){
    if (threadIdx.x < st) s[threadIdx.x] += s[threadIdx.x + st];
    __syncthreads();
  }
  if (threadIdx.x == 0) bsum[blockIdx.x] = s[0];
}

__global__ void k_scan2(int* __restrict__ bsum, int nb, int* __restrict__ row_start){
  if (blockIdx.x == 0 && threadIdx.x == 0){
    int run = 0;
    for (int b = 0; b < nb; ++b){ int v = bsum[b]; bsum[b] = run; run += v; }
    row_start[NN] = run;
  }
}

__global__ void k_scan3(const int* __restrict__ degi, const int* __restrict__ boff,
                        int* __restrict__ row_start){
  __shared__ int s[512];
  int i = blockIdx.x*512 + threadIdx.x;
  int v = (i < NN) ? degi[i] : 0;
  s[threadIdx.x] = v;
  __syncthreads();
  for (int st = 1; st < 512; st <<= 1){
    int add = (threadIdx.x >= st) ? s[threadIdx.x - st] : 0;
    __syncthreads();
    s[threadIdx.x] += add;
    __syncthreads();
  }
  if (i < NN) row_start[i] = boff[blockIdx.x] + s[threadIdx.x] - v; // exclusive
}

__global__ void k_fill(const int* __restrict__ src, const int* __restrict__ dst,
                       const int* __restrict__ row_start, int* __restrict__ cursor,
                       int* __restrict__ csr){
  int e = blockIdx.x*256 + threadIdx.x;
  if (e < NE){
    int d = dst[e];
    int p = atomicAdd(&cursor[d], 1);
    csr[row_start[d] + p] = src[e];
  }
}

// ======= thread mapping for the fused per-(node,window) kernels =======
// block = 25 nodes x 10 windows = 250 active threads (of 256).
// j = tid; n = blk*25 + j/10; t = j%10.  Node-major layouts:
//   h1/x2p: [n][t][8]  (320 B per node, 5 aligned cachelines)
//   xg    : [n][t][32] (1280 B per node)

// ---------------- conv1 matmul: h1[n][t][:] = (feat[t][n] ) @ W1 * ns[n] ----------------
__global__ __launch_bounds__(256) void k_conv1(const float* __restrict__ feat,
                                               const float* __restrict__ W1,
                                               const float* __restrict__ ns,
                                               float* __restrict__ h1){
  __shared__ float4 w[256];            // W1[d][0..3], W1[d][4..7] -> w[d*2+q]
  int tid = threadIdx.x;
  w[tid] = ((const float4*)W1)[tid];   // 256 float4 = 1024 floats
  __syncthreads();
  if (tid >= 250) return;
  int n = blockIdx.x*25 + tid/10;
  int t = tid - (tid/10)*10;
  long long r = (long long)t*NN + n;
  const float4* frow = (const float4*)feat + r*32;
  float a0x=0,a0y=0,a0z=0,a0w=0, a1x=0,a1y=0,a1z=0,a1w=0;
  #pragma unroll
  for (int d4 = 0; d4 < 32; ++d4){
    float4 f = frow[d4];
    #pragma unroll
    for (int c = 0; c < 4; ++c){
      float fv = (c==0)?f.x:((c==1)?f.y:((c==2)?f.z:f.w));
      float4 wa = w[(d4*4+c)*2 + 0];
      float4 wb = w[(d4*4+c)*2 + 1];
      a0x += fv*wa.x; a0y += fv*wa.y; a0z += fv*wa.z; a0w += fv*wa.w;
      a1x += fv*wb.x; a1y += fv*wb.y; a1z += fv*wb.z; a1w += fv*wb.w;
    }
  }
  float sc = ns[n];
  float4 o0 = { a0x*sc, a0y*sc, a0z*sc, a0w*sc };
  float4 o1 = { a1x*sc, a1y*sc, a1z*sc, a1w*sc };
  float4* out = (float4*)h1 + ((long long)n*10 + t)*2;
  out[0] = o0; out[1] = o1;
}

// ---------------- aggregate1 + conv1 epilogue (+pre-scale for layer2) ----------------
__global__ __launch_bounds__(256) void k_agg1(const float* __restrict__ h1,
                                              const int* __restrict__ row_start,
                                              const int* __restrict__ csr,
                                              const float* __restrict__ ns,
                                              const float* __restrict__ nd,
                                              const float* __restrict__ b1,
                                              float* __restrict__ x2p){
  __shared__ float b1s[8];
  int tid = threadIdx.x;
  if (tid < 8) b1s[tid] = b1[tid];
  __syncthreads();
  if (tid >= 250) return;
  int n = blockIdx.x*25 + tid/10;
  int t = tid - (tid/10)*10;
  const float4* base = (const float4*)h1;
  float a0x=0,a0y=0,a0z=0,a0w=0, a1x=0,a1y=0,a1z=0,a1w=0;
  int e0 = row_start[n], e1 = row_start[n+1];
  for (int e = e0; e < e1; ++e){
    int s = csr[e];
    long long o = ((long long)s*10 + t)*2;
    float4 v0 = base[o + 0];
    float4 v1 = base[o + 1];
    a0x += v0.x; a0y += v0.y; a0z += v0.z; a0w += v0.w;
    a1x += v1.x; a1y += v1.y; a1z += v1.z; a1w += v1.w;
  }
  float sc = nd[n];
  float osc = ns[n];  // layer-2 source-norm pre-scale folded in
  float4 o0, o1;
  o0.x = fmaxf(a0x*sc + b1s[0], 0.f)*osc;
  o0.y = fmaxf(a0y*sc + b1s[1], 0.f)*osc;
  o0.z = fmaxf(a0z*sc + b1s[2], 0.f)*osc;
  o0.w = fmaxf(a0w*sc + b1s[3], 0.f)*osc;
  o1.x = fmaxf(a1x*sc + b1s[4], 0.f)*osc;
  o1.y = fmaxf(a1y*sc + b1s[5], 0.f)*osc;
  o1.z = fmaxf(a1z*sc + b1s[6], 0.f)*osc;
  o1.w = fmaxf(a1w*sc + b1s[7], 0.f)*osc;
  float4* out = (float4*)x2p + ((long long)n*10 + t)*2;
  out[0] = o0; out[1] = o1;
}

// ---------------- aggregate2 + W2 epilogue + LSTM input projection ----------------
__global__ __launch_bounds__(256) void k_agg2(const float* __restrict__ x2p,
                                              const int* __restrict__ row_start,
                                              const int* __restrict__ csr,
                                              const float* __restrict__ nd,
                                              const float* __restrict__ W2,
                                              const float* __restrict__ b2,
                                              const float* __restrict__ Wih,
                                              const float* __restrict__ bih,
                                              const float* __restrict__ bhh,
                                              float* __restrict__ xg){
  __shared__ float w2[128];     // (8,16) row-major
  __shared__ float4 wih[128];   // (32,16) row-major as float4
  __shared__ float bsum[32];
  __shared__ float b2s[16];
  int tid = threadIdx.x;
  if (tid < 128){ w2[tid] = W2[tid]; wih[tid] = ((const float4*)Wih)[tid]; }
  if (tid < 32) bsum[tid] = bih[tid] + bhh[tid];
  if (tid < 16) b2s[tid] = b2[tid];
  __syncthreads();
  if (tid >= 250) return;
  int n = blockIdx.x*25 + tid/10;
  int t = tid - (tid/10)*10;
  const float4* base = (const float4*)x2p;
  float acc[8] = {0,0,0,0,0,0,0,0};
  int e0 = row_start[n], e1 = row_start[n+1];
  for (int e = e0; e < e1; ++e){
    int s = csr[e];
    long long o = ((long long)s*10 + t)*2;
    float4 v0 = base[o + 0];
    float4 v1 = base[o + 1];
    acc[0]+=v0.x; acc[1]+=v0.y; acc[2]+=v0.z; acc[3]+=v0.w;
    acc[4]+=v1.x; acc[5]+=v1.y; acc[6]+=v1.z; acc[7]+=v1.w;
  }
  float sc = nd[n];
  float y[16];
  #pragma unroll
  for (int j = 0; j < 16; ++j){
    float s = 0.f;
    #pragma unroll
    for (int k = 0; k < 8; ++k) s += acc[k]*w2[k*16 + j];
    y[j] = fmaxf(s*sc + b2s[j], 0.f);
  }
  // xg[n][t][g] = bsum[g] + y . Wih[g][:]
  float4* out = (float4*)xg + ((long long)n*10 + t)*8;
  #pragma unroll
  for (int g4 = 0; g4 < 8; ++g4){
    float4 o;
    #pragma unroll
    for (int c = 0; c < 4; ++c){
      int g = g4*4 + c;
      float s = bsum[g];
      #pragma unroll
      for (int q = 0; q < 4; ++q){
        float4 wv = wih[g*4 + q];
        s += y[q*4+0]*wv.x + y[q*4+1]*wv.y + y[q*4+2]*wv.z + y[q*4+3]*wv.w;
      }
      if (c==0) o.x = s; else if (c==1) o.y = s; else if (c==2) o.z = s; else o.w = s;
    }
    out[g4] = o;
  }
}

// ---------------- LSTM over T=10 + max-pool reduce ----------------
__global__ __launch_bounds__(256) void k_lstm(const float* __restrict__ xg,
                                              const float* __restrict__ Whh,
                                              unsigned* __restrict__ maxbuf){
  __shared__ float4 whh[64];   // (32,8) row-major as float4: whh[g*2+q]
  __shared__ unsigned smax[8];
  int tid = threadIdx.x;
  if (tid < 64) whh[tid] = ((const float4*)Whh)[tid];
  if (tid < 8) smax[tid] = 0u;
  __syncthreads();
  int n = blockIdx.x*256 + tid;
  if (n < NN){
    float h[8] = {0,0,0,0,0,0,0,0};
    float c[8] = {0,0,0,0,0,0,0,0};
    const float4* xr = (const float4*)xg + (long long)n*80; // [t][32] contiguous per node
    for (int t = 0; t < TW; ++t){
      float g[32];
      #pragma unroll
      for (int q = 0; q < 8; ++q){
        float4 v = xr[t*8 + q];
        g[q*4+0]=v.x; g[q*4+1]=v.y; g[q*4+2]=v.z; g[q*4+3]=v.w;
      }
      #pragma unroll
      for (int gi = 0; gi < 32; ++gi){
        float4 wa = whh[gi*2+0], wb = whh[gi*2+1];
        g[gi] += h[0]*wa.x + h[1]*wa.y + h[2]*wa.z + h[3]*wa.w
               + h[4]*wb.x + h[5]*wb.y + h[6]*wb.z + h[7]*wb.w;
      }
      #pragma unroll
      for (int j = 0; j < 8; ++j){
        float ig = sigf(g[j]);
        float fg = sigf(g[8+j]);
        float gg = tanhfast(g[16+j]);
        float og = sigf(g[24+j]);
        c[j] = fg*c[j] + ig*gg;
        h[j] = og*tanhfast(c[j]);
      }
    }
    #pragma unroll
    for (int j = 0; j < 8; ++j){
      unsigned b = __float_as_uint(h[j]);
      unsigned u = (b & 0x80000000u) ? ~b : (b | 0x80000000u); // monotonic map
      atomicMax(&smax[j], u);
    }
  }
  __syncthreads();
  if (tid < 8) atomicMax(&maxbuf[tid], smax[tid]);
}

// ---------------- head ----------------
__global__ void k_final(const unsigned* __restrict__ maxbuf,
                        const float* __restrict__ Wo, const float* __restrict__ bo,
                        float* __restrict__ out){
  if (blockIdx.x == 0 && threadIdx.x == 0){
    float m[8];
    #pragma unroll
    for (int j = 0; j < 8; ++j){
      unsigned u = maxbuf[j];
      unsigned b = (u & 0x80000000u) ? (u ^ 0x80000000u) : ~u;
      m[j] = __uint_as_float(b);
    }
    #pragma unroll
    for (int o = 0; o < 4; ++o){
      float s = bo[o];
      #pragma unroll
      for (int k = 0; k < 8; ++k) s += m[k]*Wo[k*4 + o];
      out[o] = 1.0f/(1.0f + __expf(-s));
    }
  }
}

extern "C" void kernel_launch(void* const* d_in, const int* in_sizes, int n_in,
                              void* d_out, int out_size, void* d_ws, size_t ws_size,
                              hipStream_t stream) {
  const float* feat = (const float*)d_in[0];
  const int*   src  = (const int*)d_in[1];
  const int*   dst  = (const int*)d_in[2];
  const float* W1   = (const float*)d_in[3];
  const float* b1   = (const float*)d_in[4];
  const float* W2   = (const float*)d_in[5];
  const float* b2   = (const float*)d_in[6];
  const float* Wih  = (const float*)d_in[7];
  const float* Whh  = (const float*)d_in[8];
  const float* bih  = (const float*)d_in[9];
  const float* bhh  = (const float*)d_in[10];
  const float* Wo   = (const float*)d_in[11];
  const float* bo   = (const float*)d_in[12];
  float* out = (float*)d_out;

  // workspace layout (all offsets 256B-aligned)
  const size_t SN = 50048; // padded node stride
  int*      dego      = (int*)d_ws;
  int*      degi      = dego + SN;
  int*      cursor    = degi + SN;
  float*    ns        = (float*)(cursor + SN);
  float*    nd        = ns + SN;
  int*      row_start = (int*)(nd + SN);       // 50001 used, 50304 reserved
  int*      bsum      = row_start + 50304;     // 128
  unsigned* maxbuf    = (unsigned*)(bsum + 128); // 8 used, 64 reserved
  int*      csr       = (int*)(maxbuf + 64);   // 800000
  float*    h1        = (float*)(csr + 800000);   // 4,000,000  [n][t][8]
  float*    x2p       = h1 + 4000000;             // 4,000,000  [n][t][8]
  float*    xg        = x2p + 4000000;            // 16,000,000 [n][t][32]

  hipMemsetAsync(dego, 0, 3*SN*sizeof(int), stream);

  const int B = 256;
  k_degree<<<(NE + B - 1)/B, B, 0, stream>>>(src, dst, dego, degi);
  k_norm  <<<(NN + B - 1)/B, B, 0, stream>>>(dego, degi, ns, nd, maxbuf);

  const int NB = (NN + 511)/512; // 98
  k_scan1<<<NB, 512, 0, stream>>>(degi, bsum);
  k_scan2<<<1, 64, 0, stream>>>(bsum, NB, row_start);
  k_scan3<<<NB, 512, 0, stream>>>(degi, bsum, row_start);
  k_fill <<<(NE + B - 1)/B, B, 0, stream>>>(src, dst, row_start, cursor, csr);

  const int NBLK = NN/25; // 2000 blocks, 25 nodes x 10 windows each
  k_conv1<<<NBLK, B, 0, stream>>>(feat, W1, ns, h1);
  k_agg1 <<<NBLK, B, 0, stream>>>(h1, row_start, csr, ns, nd, b1, x2p);
  k_agg2 <<<NBLK, B, 0, stream>>>(x2p, row_start, csr, nd, W2, b2, Wih, bih, bhh, xg);
  k_lstm <<<(NN + B - 1)/B, B, 0, stream>>>(xg, Whh, maxbuf);
  k_final<<<1, 64, 0, stream>>>(maxbuf, Wo, bo, out);
}